// Round 9
// baseline (738.915 us; speedup 1.0000x reference)
//
#include <hip/hip_runtime.h>
#include <cstdint>
#include <cstddef>

typedef unsigned short u16;

#define HH 256
#define IIN 128
#define TT 512
#define G3 768
#define RSTR 776    // ring row stride in u16 (768 + 8 pad: spreads row banks)

typedef __attribute__((ext_vector_type(8))) short bf16x8;
typedef __attribute__((ext_vector_type(4))) float f32x4;
typedef __attribute__((ext_vector_type(4))) int   i32x4;

__device__ __forceinline__ u16 f2bf(float f) {
    union { float f; uint32_t i; } c; c.f = f;
    uint32_t r = c.i + 0x7fffu + ((c.i >> 16) & 1u);
    return (u16)(r >> 16);
}
__device__ __forceinline__ float bf2f(u16 s) {
    union { uint32_t i; float f; } u; u.i = ((uint32_t)s) << 16; return u.f;
}
__device__ __forceinline__ float frcp(float x) { return __builtin_amdgcn_rcpf(x); }
__device__ __forceinline__ float sigm(float x) {
    float e = __expf(-fabsf(x));
    float s = frcp(1.f + e);
    return x >= 0.f ? s : 1.f - s;   // 1-s == e/(1+e)
}
__device__ __forceinline__ float tanh_f(float x) {
    float e = __expf(-2.f * fabsf(x));          // overflow-safe
    float t = (1.f - e) * frcp(1.f + e);
    return x >= 0.f ? t : -t;
}

// lgkmcnt-only barrier: drains LDS ops for cross-wave visibility but leaves
// global (vmcnt) loads/stores in flight.
#define LDS_BARRIER() asm volatile("s_waitcnt lgkmcnt(0)\n\ts_barrier" ::: "memory")

// ---------------------------------------------------------------------------
// FULLY-FUSED kernel, xg-in-LDS-ring edition. grid=256 (block b = batch b),
// block=512 (8 waves, 2/SIMD).
//
// R8 left phase 1 as a 68us serial prefix + 341 MB of HBM round-trip for xg.
// Now xg NEVER goes to global: every 16 steps a burst of 24 bf16 MFMAs/wave
// (the phase-1 M=16 tile, all rows used) produces the NEXT 16 xg rows into
// an LDS ring half [16][768] bf16 while the recurrence consumes the other
// half. Ring rows are written >=16 steps (>=16 barriers) before first read.
// Gate inputs become 3 ds_read_u16/step (hidden under MFMAs) instead of
// 3 global loads + prefetch registers. Burst cost amortized: ~58 cyc/step
// MFMA + ~55 cyc/step exposed x-load latency << the old phase.
// Numerics BITWISE IDENTICAL to R8 (same f2bf, same kt order, same
// round-trip through bf16) -> absmax must remain exactly 0.01293945.
// ---------------------------------------------------------------------------
#define GRU_STEP(TC_, HQR_, HQW_) do {                                         \
    const u16* rg_ = &ring[((TC_) >> 4) & 1][(TC_) & 15][0];                   \
    float xr = bf2f(rg_[j]);                                                   \
    float xz = bf2f(rg_[256 + j]);                                             \
    float xn = bf2f(rg_[512 + j]);                                             \
    i32x4 Cr[2] = {}, Cz[2] = {}, Cn[2] = {};                                  \
    _Pragma("unroll")                                                          \
    for (int kt = 0; kt < 4; ++kt) {                                           \
        i32x4 Aq = *(const i32x4*)((const char*)(HQR_) + kt * 64 + quad * 16); \
        Cr[0] = __builtin_amdgcn_mfma_i32_16x16x64_i8(Aq, Bq[0][0][kt], Cr[0], 0, 0, 0); \
        Cr[1] = __builtin_amdgcn_mfma_i32_16x16x64_i8(Aq, Bq[0][1][kt], Cr[1], 0, 0, 0); \
        Cz[0] = __builtin_amdgcn_mfma_i32_16x16x64_i8(Aq, Bq[1][0][kt], Cz[0], 0, 0, 0); \
        Cz[1] = __builtin_amdgcn_mfma_i32_16x16x64_i8(Aq, Bq[1][1][kt], Cz[1], 0, 0, 0); \
        Cn[0] = __builtin_amdgcn_mfma_i32_16x16x64_i8(Aq, Bq[2][0][kt], Cn[0], 0, 0, 0); \
        Cn[1] = __builtin_amdgcn_mfma_i32_16x16x64_i8(Aq, Bq[2][1][kt], Cn[1], 0, 0, 0); \
    }                                                                          \
    float dr = (float)(i16 ? Cr[1][0] : Cr[0][0]) * scG[0];                    \
    float dz = (float)(i16 ? Cz[1][0] : Cz[0][0]) * scG[1];                    \
    float dn = (float)(i16 ? Cn[1][0] : Cn[0][0]) * scG[2];                    \
    float r = sigm(xr + dr);                                                   \
    float z = sigm(xz + dz);                                                   \
    float n = tanh_f(xn + r * (dn + bhn));                                     \
    hreg = n + z * (hreg - n);                                                 \
    float hc = fminf(fmaxf(hreg, -1.f), 1.f);   /* |h|<=1 mathematically */    \
    int hq8 = (int)rintf(hc * 127.f);                                          \
    if (lane < 32) {                                                           \
        ((char*)(HQW_))[j] = (char)hq8;                                        \
        outb[(size_t)(TC_) * HH + j] = hreg;                                   \
    }                                                                          \
    LDS_BARRIER();                                                             \
} while (0)

// produce xg rows tb..tb+15 into ring[HALF_] (tb multiple of 16)
#define XG_BURST(TB_, HALF_) do {                                              \
    const float* xrow_ = x + ((size_t)b * TT + (TB_) + colL) * IIN;            \
    bf16x8 bA[4];                                                              \
    _Pragma("unroll")                                                          \
    for (int kt = 0; kt < 4; ++kt) {                                           \
        float4 lo = *(const float4*)(xrow_ + kt * 32 + quad * 8);              \
        float4 hi = *(const float4*)(xrow_ + kt * 32 + quad * 8 + 4);          \
        union { bf16x8 v; u16 s[8]; } u_;                                      \
        u_.s[0] = f2bf(lo.x); u_.s[1] = f2bf(lo.y);                            \
        u_.s[2] = f2bf(lo.z); u_.s[3] = f2bf(lo.w);                            \
        u_.s[4] = f2bf(hi.x); u_.s[5] = f2bf(hi.y);                            \
        u_.s[6] = f2bf(hi.z); u_.s[7] = f2bf(hi.w);                            \
        bA[kt] = u_.v;                                                         \
    }                                                                          \
    f32x4 C[6] = {};                                                           \
    _Pragma("unroll")                                                          \
    for (int kt = 0; kt < 4; ++kt)                                             \
        _Pragma("unroll")                                                      \
        for (int n = 0; n < 6; ++n)                                            \
            C[n] = __builtin_amdgcn_mfma_f32_16x16x32_bf16(bA[kt], Bi[n][kt], C[n], 0, 0, 0); \
    /* C layout [m89]: row = quad*4 + reg, col = lane&15 */                    \
    _Pragma("unroll")                                                          \
    for (int n = 0; n < 6; ++n) {                                              \
        int col_ = wv * 96 + n * 16 + colL;                                    \
        _Pragma("unroll")                                                      \
        for (int r = 0; r < 4; ++r)                                            \
            ring[HALF_][quad * 4 + r][col_] = f2bf(C[n][r] + bvv[n]);          \
    }                                                                          \
} while (0)

__global__ __launch_bounds__(512, 1) void gru_fused(
    const float* __restrict__ x, const float* __restrict__ W_ih,
    const float* __restrict__ W_hh,
    const float* __restrict__ b_ih, const float* __restrict__ b_hh,
    float* __restrict__ out)
{
    __shared__ u16 ring[2][16][RSTR];              // xg ring: 49,664 B
    __shared__ __align__(16) int hqBuf[2][HH / 4]; // h int8 (*127), dbuf

    const int tid = threadIdx.x;
    const int lane = tid & 63, wv = tid >> 6;       // wv in [0,8)
    const int quad = lane >> 4, colL = lane & 15;
    const int i16 = quad & 1;                       // which 16-col tile
    const int j = wv * 32 + (lane & 31);            // hidden index this lane owns
    const int b = blockIdx.x;

    // ---- W_ih -> persistent bf16 B-frags: wave owns cols [wv*96, +96) ----
    bf16x8 Bi[6][4];
    float bvv[6];
    #pragma unroll
    for (int n = 0; n < 6; ++n) {
        int col = wv * 96 + n * 16 + colL;
        const float* wr = W_ih + (size_t)col * IIN;
        #pragma unroll
        for (int kt = 0; kt < 4; ++kt) {
            float4 lo = *(const float4*)(wr + kt * 32 + quad * 8);
            float4 hi = *(const float4*)(wr + kt * 32 + quad * 8 + 4);
            union { bf16x8 v; u16 s[8]; } u;
            u.s[0] = f2bf(lo.x); u.s[1] = f2bf(lo.y);
            u.s[2] = f2bf(lo.z); u.s[3] = f2bf(lo.w);
            u.s[4] = f2bf(hi.x); u.s[5] = f2bf(hi.y);
            u.s[6] = f2bf(hi.z); u.s[7] = f2bf(hi.w);
            Bi[n][kt] = u.v;
        }
        float bv = b_ih[col];
        if (col < 512) bv += b_hh[col];     // fold b_hh into r,z pre-acts
        bvv[n] = bv;
    }

    // ---- W_hh -> per-row-scaled int8, packed 16 bytes/frag ----
    i32x4 Bq[3][2][4];
    float scG[3] = { 0.f, 0.f, 0.f };   // combined dequant rowmax/(127*127)
    #pragma unroll
    for (int g = 0; g < 3; ++g) {
        #pragma unroll
        for (int i = 0; i < 2; ++i) {
            const float* wr = W_hh + (size_t)(g * 256 + wv * 32 + i * 16 + colL) * HH;
            float m = 0.f;
            #pragma unroll
            for (int kt = 0; kt < 4; ++kt)
                #pragma unroll
                for (int u4 = 0; u4 < 4; ++u4) {
                    float4 v = *(const float4*)(wr + kt * 64 + quad * 16 + u4 * 4);
                    m = fmaxf(m, fmaxf(fmaxf(fabsf(v.x), fabsf(v.y)),
                                       fmaxf(fabsf(v.z), fabsf(v.w))));
                }
            m = fmaxf(m, __shfl_xor(m, 16));    // full row spans all 4 quads
            m = fmaxf(m, __shfl_xor(m, 32));
            float inv = m > 1e-30f ? 127.f / m : 0.f;
            float sc  = m * (1.f / 16129.f);
            #pragma unroll
            for (int kt = 0; kt < 4; ++kt) {
                int pk[4];
                #pragma unroll
                for (int u4 = 0; u4 < 4; ++u4) {
                    float4 v = *(const float4*)(wr + kt * 64 + quad * 16 + u4 * 4);
                    int q0 = (int)rintf(fminf(fmaxf(v.x * inv, -127.f), 127.f));
                    int q1 = (int)rintf(fminf(fmaxf(v.y * inv, -127.f), 127.f));
                    int q2 = (int)rintf(fminf(fmaxf(v.z * inv, -127.f), 127.f));
                    int q3 = (int)rintf(fminf(fmaxf(v.w * inv, -127.f), 127.f));
                    pk[u4] = (q0 & 255) | ((q1 & 255) << 8) | ((q2 & 255) << 16) | (q3 << 24);
                }
                i32x4 t = { pk[0], pk[1], pk[2], pk[3] };
                Bq[g][i][kt] = t;
            }
            if (i == i16) scG[g] = sc;
        }
    }

    float* outb = out + (size_t)b * TT * HH;
    const float bhn = b_hh[512 + j];
    float hreg = 0.f;                       // h0 == 0 (single chunk, T=512)

    // ---- prologue: xg rows 0..15 -> ring half 0; hq(0) = 0 ----
    XG_BURST(0, 0);
    if (tid < 64) hqBuf[0][tid] = 0;
    __syncthreads();

    for (int tc = 0; tc < TT; tc += 2) {
        GRU_STEP(tc, hqBuf[0], hqBuf[1]);
        if (((tc & 15) == 0) && (tc + 16 < TT)) {
            // produce rows tc+16..tc+31 into the half NOT being read this
            // 16-group; visible to readers via the >=15 intervening barriers.
            XG_BURST(tc + 16, ((tc >> 4) + 1) & 1);
        }
        GRU_STEP(tc + 1, hqBuf[1], hqBuf[0]);
    }
}

extern "C" void kernel_launch(void* const* d_in, const int* in_sizes, int n_in,
                              void* d_out, int out_size, void* d_ws, size_t ws_size,
                              hipStream_t stream) {
    const float* x    = (const float*)d_in[0];
    const float* W_ih = (const float*)d_in[1];
    const float* W_hh = (const float*)d_in[2];
    const float* b_ih = (const float*)d_in[3];
    const float* b_hh = (const float*)d_in[4];
    float* out = (float*)d_out;                    // fp32 output [B,T,H]
    (void)d_ws; (void)ws_size;                     // xg never leaves LDS now

    gru_fused<<<dim3(256), 512, 0, stream>>>(
        x, W_ih, W_hh, b_ih, b_hh, out);
}